// Round 10
// baseline (92.907 us; speedup 1.0000x reference)
//
#include <hip/hip_runtime.h>
#include <hip/hip_bf16.h>
#include <stdint.h>

#define NJ 21
#define ROWS_TOTAL (16384*21)      /* 344064 */
#define TILE_ROWS 63               /* 3 batches per tile (one WG) */
#define NTILES ((ROWS_TOTAL + TILE_ROWS - 1)/TILE_ROWS)  /* 5462 */
#define WPG 8                      /* 8 waves per WG; each owns one 16-feat slice */

typedef __attribute__((ext_vector_type(8))) short short8;
typedef __attribute__((ext_vector_type(4))) float f32x4;

/* wave-local LDS fence (one wave's DS ops drained; no WG barrier) */
#define WAVE_SYNC() asm volatile("s_waitcnt lgkmcnt(0)" ::: "memory")

/* hardware RNE convert — compiler emits v_cvt_pk_bf16_f32 for adjacent pairs */
__device__ __forceinline__ uint16_t f2bf(float f){
  union{ __hip_bfloat16 h; uint16_t u; } cv;
  cv.h = __float2bfloat16(f);
  return cv.u;
}

/* sXB logical (frag, slot) -> byte offset; bank-uniform, bijective, no padding */
__device__ __forceinline__ int xb_off(int frag, int slot){
  return frag*1024 + ((slot*16) ^ ((frag&7)<<4) ^ ((slot>>5)<<6));
}

/* idx<16384:  Up[frag]   = bf16( (W1@W2a)[k][n] )      (U = W1 @ W2_w[0:128])
   idx<32768:  w2bp[frag] = bf16( W2_w[128+k][n] )
   idx<34816:  stp[frag]  = B-tile [ws | wt | 0...]:  n==0 -> (W1@a1)[k], n==1 -> (W1@a2)[k]
   frag layout: buf[(tile*64 + lane)*8 + e] = M[k=32ks+8*(lane>>4)+e][n=16nt+(lane&15)] */
__global__ void pack_kernel(const float* __restrict__ W1, const float* __restrict__ W2,
                            const float* __restrict__ a,
                            uint16_t* __restrict__ Up, uint16_t* __restrict__ w2bp,
                            uint16_t* __restrict__ stp){
  int idx = blockIdx.x*256 + threadIdx.x;       /* 0..34815 */
  if (idx < 32768){
    int which = idx >> 14;
    int sub = idx & 16383;
    int e = sub & 7, lane = (sub>>3)&63, nt = (sub>>9)&7, ks = sub>>12;
    int k = 32*ks + 8*(lane>>4) + e;
    int n = 16*nt + (lane&15);
    if (which==0){
      float acc = 0.f;
      for (int p=0;p<128;++p) acc += W1[k*128+p]*W2[p*128+n];
      Up[sub] = f2bf(acc);
    } else {
      w2bp[sub] = f2bf(W2[(128+k)*128+n]);
    }
  } else if (idx < 34816){
    int sub = idx - 32768;        /* 0..2047 */
    int e = sub & 7, lane = (sub>>3)&63, ks = (sub>>9)&3;
    int k = 32*ks + 8*(lane>>4) + e;
    int l15 = lane & 15;
    float v = 0.f;
    if (l15 == 0){ for (int p=0;p<128;++p) v += W1[k*128+p]*a[p]; }
    else if (l15 == 1){ for (int p=0;p<128;++p) v += W1[k*128+p]*a[128+p]; }
    stp[sub] = f2bf(v);
  }
}

__global__ __launch_bounds__(512,8) void camgat_kernel(
    const float* __restrict__ x, const float* __restrict__ cam,
    const float* __restrict__ bias,
    const uint16_t* __restrict__ Up, const uint16_t* __restrict__ w2bp,
    const uint16_t* __restrict__ stp,
    float* __restrict__ out)
{
  __shared__ uint16_t sXB[4*4*64*8];     /* x A-frags, bank-uniform layout, 16KB */
  __shared__ uint16_t sALPHA[64*64];     /* block-diag alpha, swizzled, 8KB */
  __shared__ uint16_t sUT[WPG][16*64];   /* per-wave u^T slice [feat16][sample64], 2KB each */
  /* overlays (regions only touched AFTER barrier 2 by their owner waves):
     sST  -> sUT[0][0..255]  : s,t rows, used between barrier 1 and 2
     sCAM -> sUT[1][0..881]  : cam matrix, read by wave0 softmax before barrier 2 */
  float* sST  = (float*)&sUT[0][0];      /* sST[0..63]=s, sST[64..127]=t */
  float* sCAM = (float*)&sUT[1][0];      /* 441 floats */

  const int tid  = threadIdx.x;
  const int wv   = tid >> 6;
  const int lane = tid & 63;
  const int g = lane >> 4;
  const int l15 = lane & 15;
  const int row_base = blockIdx.x * TILE_ROWS;

  uint16_t* myUT = sUT[wv];

  /* one precomputed lane address; per-frag XOR is a compile-time constant */
  const int laneoff = (lane*16) ^ ((lane>>5)<<6);
  #define LDXF(mi,ks) (*(const short8*)((char*)sXB + (((mi)*4+(ks))*1024) \
                        + (laneoff ^ ((((mi)*4+(ks))&7)<<4))))

  /* ---- 0a: cooperative alpha zero (512 x 16B = 8KB) ---- */
  {
    uint4 z4; z4.x=0; z4.y=0; z4.z=0; z4.w=0;
    ((uint4*)sALPHA)[tid] = z4;
  }
  /* ---- 0a': stage cam -> LDS (overlay on sUT[1]) ---- */
  if (tid < NJ*NJ) sCAM[tid] = cam[tid];

  /* ---- 0b: cooperative x -> bf16 frags (thread: 1 row x 16 cols) ---- */
  {
    int r   = tid >> 3;           /* 0..63 */
    int c16 = (tid & 7) * 16;     /* col group */
    int smi = r >> 4, sl15 = r & 15;
    int ks  = c16 >> 5;
    int g0  = (c16 & 31) >> 3;    /* 0 or 2 */
    int frag = smi*4 + ks;
    long grow = (long)row_base + r;
    bool valid = (r < TILE_ROWS) && (grow < (long)ROWS_TOTAL);
    const float* xrow = x + (valid ? grow : 0)*128 + c16;
    float4 v0 = *(const float4*)(xrow + 0);
    float4 v1 = *(const float4*)(xrow + 4);
    float4 v2 = *(const float4*)(xrow + 8);
    float4 v3 = *(const float4*)(xrow + 12);
    if (!valid){ v0 = make_float4(0.f,0.f,0.f,0.f); v1=v0; v2=v0; v3=v0; }
    uint4 w0, w1;
    w0.x = (uint32_t)f2bf(v0.x) | ((uint32_t)f2bf(v0.y)<<16);
    w0.y = (uint32_t)f2bf(v0.z) | ((uint32_t)f2bf(v0.w)<<16);
    w0.z = (uint32_t)f2bf(v1.x) | ((uint32_t)f2bf(v1.y)<<16);
    w0.w = (uint32_t)f2bf(v1.z) | ((uint32_t)f2bf(v1.w)<<16);
    w1.x = (uint32_t)f2bf(v2.x) | ((uint32_t)f2bf(v2.y)<<16);
    w1.y = (uint32_t)f2bf(v2.z) | ((uint32_t)f2bf(v2.w)<<16);
    w1.z = (uint32_t)f2bf(v3.x) | ((uint32_t)f2bf(v3.y)<<16);
    w1.w = (uint32_t)f2bf(v3.z) | ((uint32_t)f2bf(v3.w)<<16);
    int s1 = 16*g0 + sl15;
    *(uint4*)((char*)sXB + xb_off(frag, s1))      = w0;
    *(uint4*)((char*)sXB + xb_off(frag, s1+16))   = w1;
  }

  /* ---- 0c: prefetch own weight frags pre-barrier ---- */
  short8 bfu[4];
  #pragma unroll
  for (int ks=0;ks<4;++ks)
    bfu[ks] = *(const short8*)(Up + (size_t)(((ks*8)+wv)*64 + lane)*8);
  short8 stf[4];
  if (wv == 0){
    #pragma unroll
    for (int ks=0;ks<4;++ks)
      stf[ks] = *(const short8*)(stp + (size_t)(ks*64 + lane)*8);
  }
  __syncthreads();

  /* ---- 1: wave 0 only: s,t via st-MFMA, then softmax for all rows ---- */
  if (wv == 0){
    f32x4 stacc[4];
    { f32x4 z; z[0]=0.f; z[1]=0.f; z[2]=0.f; z[3]=0.f;
      #pragma unroll
      for (int mi=0;mi<4;++mi) stacc[mi]=z; }
    #pragma unroll
    for (int ks=0;ks<4;++ks)
      #pragma unroll
      for (int mi=0;mi<4;++mi)
        stacc[mi] = __builtin_amdgcn_mfma_f32_16x16x32_bf16(LDXF(mi,ks), stf[ks], stacc[mi], 0,0,0);
    /* scatter: C layout col=l15 (0->s, 1->t), row=16mi+4g+q */
    if (l15 < 2){
      #pragma unroll
      for (int mi=0;mi<4;++mi)
        #pragma unroll
        for (int q=0;q<4;++q)
          sST[64*l15 + 16*mi+4*g+q] = stacc[mi][q];
    }
    WAVE_SYNC();   /* sST visible wave-wide */

    if (lane < TILE_ROWS){
      int r = lane;
      int qq = (r>=42)?2:((r>=21)?1:0);
      int i = r - 21*qq, base = 21*qq;
      float s_r = sST[r];
      float ev[NJ]; float m = -1e30f;
      #pragma unroll
      for (int j=0;j<NJ;++j){
        float e = s_r + sST[64 + base+j];
        e = e>0.f ? e : 0.2f*e;
        ev[j]=e; m = fmaxf(m,e);
      }
      float sum=0.f;
      #pragma unroll
      for (int j=0;j<NJ;++j){ float p = __expf(ev[j]-m); ev[j]=p; sum+=p; }
      float inv = 1.f/sum;
      #pragma unroll
      for (int j=0;j<NJ;++j){
        uint16_t ab = f2bf(sCAM[i*NJ+j]*ev[j]*inv);
        int addr = (r*128 + (base+j)*2) ^ ((r&7)<<4);
        *(uint16_t*)((char*)sALPHA + addr) = ab;
      }
    }
  }
  __syncthreads();   /* alpha complete; sXB/sALPHA read-only hereafter */

  /* ---- 2: this wave's 16-feature slice (ntile = wv) ---- */
  /* u-GEMM slice: M64 N16 K128 */
  f32x4 uacc[4];
  { f32x4 z; z[0]=0.f; z[1]=0.f; z[2]=0.f; z[3]=0.f;
    #pragma unroll
    for (int mi=0;mi<4;++mi) uacc[mi]=z; }
  #pragma unroll
  for (int ks=0;ks<4;++ks)
    #pragma unroll
    for (int mi=0;mi<4;++mi)
      uacc[mi] = __builtin_amdgcn_mfma_f32_16x16x32_bf16(LDXF(mi,ks), bfu[ks], uacc[mi], 0,0,0);

  /* pack u^T slice -> own LDS: [feat_local=l15][sample], swizzled */
  #pragma unroll
  for (int mi=0;mi<4;++mi){
    uint32_t lo = (uint32_t)f2bf(uacc[mi][0]) | ((uint32_t)f2bf(uacc[mi][1])<<16);
    uint32_t hi = (uint32_t)f2bf(uacc[mi][2]) | ((uint32_t)f2bf(uacc[mi][3])<<16);
    int addr = (l15*128 + (16*mi + 4*g)*2) ^ ((l15&7)<<4);
    uint2 w; w.x=lo; w.y=hi;
    *(uint2*)((char*)myUT + addr) = w;
  }

  /* w2b-GEMM slice (hides uT write drain + bfw load latency) */
  short8 bfw[4];
  #pragma unroll
  for (int ks=0;ks<4;++ks)
    bfw[ks] = *(const short8*)(w2bp + (size_t)(((ks*8)+wv)*64 + lane)*8);
  f32x4 oacc[4];
  {
    float b = bias[16*wv + l15];
    f32x4 bv; bv[0]=b; bv[1]=b; bv[2]=b; bv[3]=b;
    #pragma unroll
    for (int mi=0;mi<4;++mi) oacc[mi]=bv;
  }
  #pragma unroll
  for (int ks=0;ks<4;++ks)
    #pragma unroll
    for (int mi=0;mi<4;++mi)
      oacc[mi] = __builtin_amdgcn_mfma_f32_16x16x32_bf16(LDXF(mi,ks), bfw[ks], oacc[mi], 0,0,0);

  WAVE_SYNC();   /* own uT writes visible */

  /* oacc += alpha @ u-slice  (M64 N16 K64) */
  #pragma unroll
  for (int ks2=0;ks2<2;++ks2){
    int kb = (32*ks2 + 8*g)*2;
    short8 bfr = *(const short8*)((char*)myUT + ((l15*128 + kb) ^ ((l15&7)<<4)));
    #pragma unroll
    for (int mi=0;mi<4;++mi){
      int i = 16*mi + l15;
      short8 afr = *(const short8*)((char*)sALPHA + ((i*128 + kb) ^ ((i&7)<<4)));
      oacc[mi] = __builtin_amdgcn_mfma_f32_16x16x32_bf16(afr, bfr, oacc[mi], 0,0,0);
    }
  }

  /* ELU + predicated store of this 16-col slice */
  #pragma unroll
  for (int mi=0;mi<4;++mi){
    #pragma unroll
    for (int q=0;q<4;++q){
      int r = 16*mi + 4*g + q;
      long grow = (long)row_base + r;
      if (r < TILE_ROWS && grow < (long)ROWS_TOTAL){
        float v = oacc[mi][q];
        v = v > 0.f ? v : (__expf(v) - 1.f);
        out[grow*128 + 16*wv + l15] = v;
      }
    }
  }
  #undef LDXF
}

extern "C" void kernel_launch(void* const* d_in, const int* in_sizes, int n_in,
                              void* d_out, int out_size, void* d_ws, size_t ws_size,
                              hipStream_t stream) {
  const float* x   = (const float*)d_in[0];
  const float* cam = (const float*)d_in[1];
  const float* W1  = (const float*)d_in[2];
  const float* a   = (const float*)d_in[3];
  const float* W2w = (const float*)d_in[4];
  const float* W2b = (const float*)d_in[5];
  float* out = (float*)d_out;

  char* ws = (char*)d_ws;
  uint16_t* Up   = (uint16_t*)(ws + 0);
  uint16_t* w2bp = (uint16_t*)(ws + 32768);
  uint16_t* stp  = (uint16_t*)(ws + 65536);

  pack_kernel<<<136, 256, 0, stream>>>(W1, W2w, a, Up, w2bp, stp);
  camgat_kernel<<<NTILES, 64*WPG, 0, stream>>>(x, cam, W2b, Up, w2bp, stp, out);
}